// Round 10
// baseline (665.188 us; speedup 1.0000x reference)
//
#include <hip/hip_runtime.h>
#include <cstddef>
#include <cstdint>

typedef __attribute__((ext_vector_type(8))) short bf16x8;
typedef __attribute__((ext_vector_type(4))) float f32x4;

static __device__ __forceinline__ short f2bf(float f) {
    union { float f; unsigned u; } x;
    x.f = f;
    unsigned r = (x.u + 0x7FFFu + ((x.u >> 16) & 1u)) >> 16;  // RNE
    return (short)r;
}

typedef __attribute__((address_space(3))) unsigned lds_u;
typedef const __attribute__((address_space(1))) unsigned glb_u;
static __device__ __forceinline__ void gld_lds16(const void* g, void* l) {
    __builtin_amdgcn_global_load_lds((glb_u*)g, (lds_u*)l, 16, 0, 0);
}

// ---------------------------------------------------------------------------
// Grid barrier, contention-safe version (R9's atomicAdd-poll cost 113us/bar:
// RMW polling from 512 waves serializes on one line). Arrivals spread over 8
// sub-counters (one 128B line each, indexed bid&7); polling is READ-ONLY
// (__hip_atomic_load, agent scope) of the 8 monotone counters + s_sleep
// backoff. Monotone phase targets (512/1024/1536) keep it race-free: a block
// reaches phase p+1 only after sum>=512*p, so overshoot never false-releases.
// All 512 blocks provably co-resident: 64KB LDS x 2/CU, launch_bounds(256,2).
// ---------------------------------------------------------------------------
static __device__ __forceinline__ void gbar(unsigned* ctrs, unsigned target) {
    asm volatile("s_waitcnt vmcnt(0) lgkmcnt(0)" ::: "memory");
    __threadfence();                       // release: writeback to coherent point
    __syncthreads();
    if (threadIdx.x == 0) {
        __hip_atomic_fetch_add(&ctrs[(blockIdx.x & 7) * 32], 1u,
                               __ATOMIC_RELEASE, __HIP_MEMORY_SCOPE_AGENT);
        for (;;) {
            unsigned sum = 0;
            #pragma unroll
            for (int i = 0; i < 8; ++i)
                sum += __hip_atomic_load(&ctrs[i * 32], __ATOMIC_ACQUIRE,
                                         __HIP_MEMORY_SCOPE_AGENT);
            if (sum >= target) break;
            __builtin_amdgcn_s_sleep(16);
        }
    }
    __syncthreads();
    __threadfence();                       // acquire: discard stale lines
}

// ---------------------------------------------------------------------------
// Pipelined bf16 GEMM core: acc += A[bm:+128,:K] @ BT[bn:+128,:K]^T.
// 3 LDS buffers, prefetch distance 2, counted vmcnt(4) + raw s_barrier.
// ---------------------------------------------------------------------------
static __device__ __forceinline__ void gemm_core(
    const short* __restrict__ A, const short* __restrict__ BT, int K,
    int bm, int bn, short* As, short* Bs, f32x4 acc[4][4])
{
    const int tid  = threadIdx.x;
    const int lane = tid & 63;
    const int wave = tid >> 6;
    const int lm   = lane & 15;
    const int quad = lane >> 4;
    const int wm = (wave >> 1) * 64;
    const int wn = (wave & 1) * 64;
    const int c = tid >> 7, r = tid & 127;   // staging coords

    const short* Ag = &A[(size_t)(bm + r) * K + c * 8];
    const short* Bg = &BT[(size_t)(bn + r) * K + c * 8];

    // prologue: step 0 -> buf0, step 1 -> buf1 (4 DMA ops per thread per step)
    gld_lds16(Ag,      &As[tid * 8]);
    gld_lds16(Ag + 16, &As[(tid + 256) * 8]);
    gld_lds16(Bg,      &Bs[tid * 8]);
    gld_lds16(Bg + 16, &Bs[(tid + 256) * 8]);
    Ag += 32; Bg += 32;
    gld_lds16(Ag,      &As[4096 + tid * 8]);
    gld_lds16(Ag + 16, &As[4096 + (tid + 256) * 8]);
    gld_lds16(Bg,      &Bs[4096 + tid * 8]);
    gld_lds16(Bg + 16, &Bs[4096 + (tid + 256) * 8]);
    Ag += 32; Bg += 32;

    const int NT = K >> 5;
    int ocur = 0;            // LDS short-offset of step t
    int onxt = 2 * 4096;     // LDS short-offset for step t+2
    for (int t = 0; t < NT; ++t) {
        if (t < NT - 1) asm volatile("s_waitcnt vmcnt(4)" ::: "memory");
        else            asm volatile("s_waitcnt vmcnt(0)" ::: "memory");
        __builtin_amdgcn_s_barrier();
        __builtin_amdgcn_sched_barrier(0);
        if (t < NT - 2) {   // stage step t+2 (its prev readers done at t-1)
            gld_lds16(Ag,      &As[onxt + tid * 8]);
            gld_lds16(Ag + 16, &As[onxt + (tid + 256) * 8]);
            gld_lds16(Bg,      &Bs[onxt + tid * 8]);
            gld_lds16(Bg + 16, &Bs[onxt + (tid + 256) * 8]);
            Ag += 32; Bg += 32;
        }
        const short* Ac = As + ocur;
        const short* Bc = Bs + ocur;
        bf16x8 af[4], bfr[4];
        #pragma unroll
        for (int i = 0; i < 4; ++i)
            af[i] = *(const bf16x8*)&Ac[(quad * 128 + wm + i * 16 + lm) * 8];
        #pragma unroll
        for (int j = 0; j < 4; ++j)
            bfr[j] = *(const bf16x8*)&Bc[(quad * 128 + wn + j * 16 + lm) * 8];
        __builtin_amdgcn_s_setprio(1);
        #pragma unroll
        for (int i = 0; i < 4; ++i)
            #pragma unroll
            for (int j = 0; j < 4; ++j)
                acc[i][j] = __builtin_amdgcn_mfma_f32_16x16x32_bf16(
                    af[i], bfr[j], acc[i][j], 0, 0, 0);
        __builtin_amdgcn_s_setprio(0);
        ocur += 4096; if (ocur == 12288) ocur = 0;
        onxt += 4096; if (onxt == 12288) onxt = 0;
    }
}

// ---------------------------------------------------------------------------
// ONE kernel, 512 blocks x 256 threads, 4 phases + 3 grid barriers:
//   P0 prep: fp32->bf16 convert (14 units/block) + weight transpose (3/block)
//   P1 qkv:  512 GEMM tiles; V-tiles write transposed+permuted straight to vT
//   P2 attn: flash attention, in-register P, KVBLK=128 (R8-verified body)
//   P3 ogemm: 256 tiles (blocks >=256 return after barrier 3)
// LDS: 64 KB union (qkv/ogemm 48K, attn 64K) -> 2 blocks/CU, 512 co-resident.
// ---------------------------------------------------------------------------
__global__ __launch_bounds__(256, 2) void mega_kernel(
    const float* __restrict__ x, const float* __restrict__ ctx,
    const float* __restrict__ Wq, const float* __restrict__ Wk,
    const float* __restrict__ Wv, const float* __restrict__ Wo,
    const float* __restrict__ bo,
    short* __restrict__ xb, short* __restrict__ cb,
    short* __restrict__ wqT, short* __restrict__ wkvT, short* __restrict__ woT,
    short* __restrict__ qb, short* __restrict__ kvb, short* __restrict__ vT,
    short* __restrict__ ob, float* __restrict__ out, unsigned* __restrict__ ctr)
{
    __shared__ __align__(16) char SMEM[65536];
    const int bid = blockIdx.x;
    const int tid = threadIdx.x;

    // ======================= P0: convert + wtrans ==========================
    {
        #pragma unroll 1
        for (int it = 0; it < 14; ++it) {
            int i = (bid + it * 512) * 256 + tid;
            const float* src; short* dst; int off;
            if (i < 1048576) { src = x; dst = xb; off = i; }
            else { src = ctx; dst = cb; off = i - 1048576; }
            float4 v = ((const float4*)src)[off];
            ushort4 w;
            w.x = (unsigned short)f2bf(v.x); w.y = (unsigned short)f2bf(v.y);
            w.z = (unsigned short)f2bf(v.z); w.w = (unsigned short)f2bf(v.w);
            ((ushort4*)dst)[off] = w;
        }
        float (*T)[33] = (float(*)[33])SMEM;
        #pragma unroll 1
        for (int it = 0; it < 3; ++it) {
            int w0 = bid + it * 512;
            int z = w0 / 384, rem = w0 % 384;
            int yt = rem >> 4, xt = rem & 15;
            const float* src; short* dst; int R;
            if (z == 0)      { src = Wq; dst = wqT;  R = 512; }
            else if (z == 1) { src = Wk; dst = wkvT; R = 768; }
            else if (z == 2) { src = Wv; dst = wkvT + (size_t)512 * 768; R = 768; }
            else             { src = Wo; dst = woT;  R = 512; }
            const bool act = (yt * 32 < R);   // block-uniform
            if (act) {
                int r = tid >> 3, c4 = (tid & 7) * 4;
                float4 v = *(const float4*)&src[(size_t)(yt * 32 + r) * 512 + xt * 32 + c4];
                T[r][c4] = v.x; T[r][c4 + 1] = v.y; T[r][c4 + 2] = v.z; T[r][c4 + 3] = v.w;
            }
            __syncthreads();
            if (act) {
                int cc = tid >> 3, r4 = (tid & 7) * 4;
                ushort4 w;
                w.x = (unsigned short)f2bf(T[r4][cc]);     w.y = (unsigned short)f2bf(T[r4 + 1][cc]);
                w.z = (unsigned short)f2bf(T[r4 + 2][cc]); w.w = (unsigned short)f2bf(T[r4 + 3][cc]);
                *(ushort4*)&dst[(size_t)(xt * 32 + cc) * R + yt * 32 + r4] = w;
            }
            __syncthreads();
        }
    }
    gbar(ctr, 512);

    // ======================= P1: qkv (+ fused vtrans) ======================
    {
        short* As = (short*)SMEM;
        short* Bs = (short*)(SMEM + 24576);
        const int L = (bid & 7) * 64 + (bid >> 3);   // bijective XCD remap, 512
        const short *A, *BT; int K, bm, bn;
        if (L < 256) { A = xb; BT = wqT;  K = 512; bm = (L >> 2) * 128; bn = (L & 3) * 128; }
        else { int b2 = L - 256; A = cb; BT = wkvT; K = 768;
               bm = (b2 >> 3) * 128; bn = (b2 & 7) * 128; }

        f32x4 acc[4][4] = {};
        gemm_core(A, BT, K, bm, bn, As, Bs, acc);

        const int lane = tid & 63, wave = tid >> 6;
        const int lm = lane & 15, quad = lane >> 4;
        const int wm = (wave >> 1) * 64, wn = (wave & 1) * 64;
        if (L < 256) {
            // Q: scaled by C1 = 0.125*log2(e) so attn softmax is exp2(S)
            #pragma unroll
            for (int j = 0; j < 4; ++j) {
                int col = bn + wn + j * 16 + lm;
                #pragma unroll
                for (int i = 0; i < 4; ++i) {
                    int row0 = bm + wm + i * 16 + quad * 4;
                    #pragma unroll
                    for (int r = 0; r < 4; ++r)
                        qb[(size_t)(row0 + r) * 512 + col] = f2bf(acc[i][j][r] * 0.18033688f);
                }
            }
        } else if (bn < 512) {
            // K half: plain write to kvb (ld 1024, cols 0..511)
            #pragma unroll
            for (int j = 0; j < 4; ++j) {
                int col = bn + wn + j * 16 + lm;
                #pragma unroll
                for (int i = 0; i < 4; ++i) {
                    int row0 = bm + wm + i * 16 + quad * 4;
                    #pragma unroll
                    for (int r = 0; r < 4; ++r)
                        kvb[(size_t)(row0 + r) * 1024 + col] = f2bf(acc[i][j][r]);
                }
            }
        } else {
            // V half: transposed + per-64-permuted direct write to vT
            const int bq = bm >> 10;
            const int nbase = (bm & 1023) + wm;
            #pragma unroll
            for (int j = 0; j < 4; ++j) {
                int dimp = bn + wn + j * 16 + lm - 512;
                short* drow = &vT[((size_t)(bq * 512 + dimp)) * 1024];
                #pragma unroll
                for (int i = 0; i < 4; ++i) {
                    int n0 = nbase + i * 16 + quad * 4;     // n0 & 3 == 0
                    int nl = n0 & 63;
                    int g  = ((nl >> 5) << 2) | ((nl >> 2) & 3);
                    int p  = (n0 & ~63) | (g << 3) | (((nl >> 4) & 1) << 2);
                    ushort4 w;
                    w.x = (unsigned short)f2bf(acc[i][j][0]);
                    w.y = (unsigned short)f2bf(acc[i][j][1]);
                    w.z = (unsigned short)f2bf(acc[i][j][2]);
                    w.w = (unsigned short)f2bf(acc[i][j][3]);
                    *(ushort4*)&drow[p] = w;
                }
            }
        }
    }
    gbar(ctr, 1024);

    // ======================= P2: attn (R8-verified body) ===================
    {
        short* Ks = (short*)SMEM;
        short* Vs = (short*)(SMEM + 32768);
        const int lane = tid & 63;
        const int wave = tid >> 6;
        const int lm   = lane & 15;
        const int quad = lane >> 4;

        const int xcdq = bid >> 3;                       // 0..63
        const int hb = (bid & 7) + ((xcdq >> 4) << 3);   // 0..31
        const int qt = xcdq & 15;                        // 0..15 (128-row tiles)
        const int h = hb & 7, b = hb >> 3;

        const size_t qrow0 = (size_t)b * 2048 + qt * 128;
        const size_t krow0 = (size_t)b * 1024;
        const int hcol = h * 64;
        const size_t vrow0 = ((size_t)b * 8 + h) * 64;

        const int rk = tid & 127, ck = tid >> 7;
        const int dv = tid & 63,  nv = tid >> 6;
        const short* kg = &kvb[(krow0 + rk) * 1024 + hcol + ck * 8];
        const short* vg = &vT[(vrow0 + dv) * 1024 + nv * 8];

        // prologue: stage tile 0 (8 DMA ops per thread)
        #pragma unroll
        for (int c = 0; c < 4; ++c)
            gld_lds16(kg + c * 16, &Ks[((ck + 2 * c) * 128 + rk) * 8]);
        #pragma unroll
        for (int c = 0; c < 4; ++c)
            gld_lds16(vg + c * 32, &Vs[((nv + 4 * c) * 64 + dv) * 8]);
        kg += 128 * 1024; vg += 128;

        const short* qrow0p = &qb[(qrow0 + wave * 32 + lm) * 512 + hcol];
        const short* qrow1p = qrow0p + 16 * 512;
        bf16x8 qf00 = *(const bf16x8*)&qrow0p[quad * 8];
        bf16x8 qf01 = *(const bf16x8*)&qrow0p[32 + quad * 8];
        bf16x8 qf10 = *(const bf16x8*)&qrow1p[quad * 8];
        bf16x8 qf11 = *(const bf16x8*)&qrow1p[32 + quad * 8];
        asm volatile("" :: "v"(qf00), "v"(qf01), "v"(qf10), "v"(qf11));

        f32x4 oacc[2][4] = {};
        float lsum[2] = {0.0f, 0.0f};
        const int frk = (quad * 128 + lm) * 8;
        const int frv = (quad * 64 + lm) * 8;

        for (int t = 0; t < 8; ++t) {
            asm volatile("s_waitcnt vmcnt(0)" ::: "memory");
            __builtin_amdgcn_s_barrier();
            __builtin_amdgcn_sched_barrier(0);
            const short* Kc = &Ks[(t & 1) * 8192];
            const short* Vc = &Vs[(t & 1) * 8192];
            if (t < 7) {
                short* Kn = &Ks[((t & 1) ^ 1) * 8192];
                short* Vn = &Vs[((t & 1) ^ 1) * 8192];
                #pragma unroll
                for (int c = 0; c < 4; ++c)
                    gld_lds16(kg + c * 16, &Kn[((ck + 2 * c) * 128 + rk) * 8]);
                #pragma unroll
                for (int c = 0; c < 4; ++c)
                    gld_lds16(vg + c * 32, &Vn[((nv + 4 * c) * 64 + dv) * 8]);
                kg += 128 * 1024; vg += 128;
            }

            // S^T = K @ Q^T
            f32x4 s0[8], s1[8];
            #pragma unroll
            for (int j = 0; j < 8; ++j) { s0[j] = (f32x4){}; s1[j] = (f32x4){}; }
            __builtin_amdgcn_s_setprio(1);
            #pragma unroll
            for (int j = 0; j < 8; ++j) {
                bf16x8 kf0 = *(const bf16x8*)&Kc[frk + j * 128];
                bf16x8 kf1 = *(const bf16x8*)&Kc[frk + 4096 + j * 128];
                s0[j] = __builtin_amdgcn_mfma_f32_16x16x32_bf16(kf0, qf00, s0[j], 0, 0, 0);
                s1[j] = __builtin_amdgcn_mfma_f32_16x16x32_bf16(kf0, qf10, s1[j], 0, 0, 0);
                s0[j] = __builtin_amdgcn_mfma_f32_16x16x32_bf16(kf1, qf01, s0[j], 0, 0, 0);
                s1[j] = __builtin_amdgcn_mfma_f32_16x16x32_bf16(kf1, qf11, s1[j], 0, 0, 0);
            }
            __builtin_amdgcn_s_setprio(0);

            // P = exp2(S); pack pairs to bf16 in-register (PV A-fragments)
            union { unsigned u[4]; bf16x8 v; } pf0[4], pf1[4];
            #pragma unroll
            for (int j = 0; j < 8; ++j) {
                #pragma unroll
                for (int rp = 0; rp < 2; ++rp) {
                    float a0 = __builtin_amdgcn_exp2f(s0[j][2 * rp]);
                    float a1 = __builtin_amdgcn_exp2f(s0[j][2 * rp + 1]);
                    float b0 = __builtin_amdgcn_exp2f(s1[j][2 * rp]);
                    float b1 = __builtin_amdgcn_exp2f(s1[j][2 * rp + 1]);
                    lsum[0] += a0 + a1;
                    lsum[1] += b0 + b1;
                    unsigned pa, pb;
                    asm("v_cvt_pk_bf16_f32 %0, %1, %2" : "=v"(pa) : "v"(a0), "v"(a1));
                    asm("v_cvt_pk_bf16_f32 %0, %1, %2" : "=v"(pb) : "v"(b0), "v"(b1));
                    pf0[j >> 1].u[(j & 1) * 2 + rp] = pa;
                    pf1[j >> 1].u[(j & 1) * 2 + rp] = pb;
                }
            }

            // O += P @ V
            __builtin_amdgcn_s_setprio(1);
            #pragma unroll
            for (int jd = 0; jd < 4; ++jd) {
                #pragma unroll
                for (int s = 0; s < 4; ++s) {
                    bf16x8 vf = *(const bf16x8*)&Vc[frv + s * 2048 + jd * 128];
                    oacc[0][jd] = __builtin_amdgcn_mfma_f32_16x16x32_bf16(pf0[s].v, vf, oacc[0][jd], 0, 0, 0);
                    oacc[1][jd] = __builtin_amdgcn_mfma_f32_16x16x32_bf16(pf1[s].v, vf, oacc[1][jd], 0, 0, 0);
                }
            }
            __builtin_amdgcn_s_setprio(0);
        }

        #pragma unroll
        for (int g = 0; g < 2; ++g) {
            float s = lsum[g];
            s += __shfl_xor(s, 16);
            s += __shfl_xor(s, 32);
            const float inv = 1.0f / s;
            float invr[4];
            #pragma unroll
            for (int r = 0; r < 4; ++r)
                invr[r] = __shfl(inv, quad * 20 + r);
            #pragma unroll
            for (int j = 0; j < 4; ++j) {
                int col = hcol + j * 16 + lm;
                #pragma unroll
                for (int r = 0; r < 4; ++r) {
                    size_t row = qrow0 + wave * 32 + g * 16 + quad * 4 + r;
                    ob[row * 512 + col] = f2bf(oacc[g][j][r] * invr[r]);
                }
            }
        }
    }
    gbar(ctr, 1536);

    // ======================= P3: ogemm (blocks 0..255) =====================
    if (bid >= 256) return;
    {
        short* As = (short*)SMEM;
        short* Bs = (short*)(SMEM + 24576);
        const int L = (bid & 7) * 32 + (bid >> 3);   // bijective, 256
        const int bm = (L >> 2) * 128, bn = (L & 3) * 128;

        f32x4 acc[4][4] = {};
        gemm_core(ob, woT, 512, bm, bn, As, Bs, acc);

        const int lane = tid & 63, wave = tid >> 6;
        const int lm = lane & 15, quad = lane >> 4;
        const int wm = (wave >> 1) * 64, wn = (wave & 1) * 64;
        #pragma unroll
        for (int j = 0; j < 4; ++j) {
            int col = bn + wn + j * 16 + lm;
            float bv = bo[col];
            #pragma unroll
            for (int i = 0; i < 4; ++i) {
                int row0 = bm + wm + i * 16 + quad * 4;
                #pragma unroll
                for (int r = 0; r < 4; ++r)
                    out[(size_t)(row0 + r) * 512 + col] = acc[i][j][r] + bv;
            }
        }
    }
}

// ---------------------------------------------------------------------------
extern "C" void kernel_launch(void* const* d_in, const int* in_sizes, int n_in,
                              void* d_out, int out_size, void* d_ws, size_t ws_size,
                              hipStream_t stream)
{
    const float* x   = (const float*)d_in[0];
    const float* ctx = (const float*)d_in[1];
    const float* Wq  = (const float*)d_in[2];
    const float* Wk  = (const float*)d_in[3];
    const float* Wv  = (const float*)d_in[4];
    const float* Wo  = (const float*)d_in[5];
    const float* bo  = (const float*)d_in[6];

    char* ws = (char*)d_ws;
    short* xb   = (short*)(ws);                                    // 8 MB
    short* cb   = (short*)(ws + (8u << 20));                       // 6 MB
    short* wqT  = (short*)(ws + (14u << 20));                      // 0.5 MB
    short* wkvT = (short*)(ws + (14u << 20) + (512u << 10));       // 1.5 MB
    short* woT  = (short*)(ws + (16u << 20));                      // 0.5 MB
    short* qb   = (short*)(ws + (16u << 20) + (512u << 10));       // 8 MB
    short* kvb  = (short*)(ws + (24u << 20) + (512u << 10));       // 8 MB
    short* vT   = (short*)(ws + (33u << 20));                      // 4 MB
    short* ob   = (short*)(ws + (38u << 20));                      // 8 MB
    unsigned* ctr = (unsigned*)(ws + (48u << 20));                 // 1 KB (8 x 128B)
    float* outp = (float*)d_out;

    hipMemsetAsync(ctr, 0, 1024, stream);
    mega_kernel<<<512, 256, 0, stream>>>(
        x, ctx, Wq, Wk, Wv, Wo, bo, xb, cb, wqT, wkvT, woT,
        qb, kvb, vT, ob, outp, ctr);
}

// Round 11
// 163.978 us; speedup vs baseline: 4.0566x; 4.0566x over previous
//
#include <hip/hip_runtime.h>
#include <cstddef>
#include <cstdint>

typedef __attribute__((ext_vector_type(8))) short bf16x8;
typedef __attribute__((ext_vector_type(4))) float f32x4;

static __device__ __forceinline__ short f2bf(float f) {
    union { float f; unsigned u; } x;
    x.f = f;
    unsigned r = (x.u + 0x7FFFu + ((x.u >> 16) & 1u)) >> 16;  // RNE
    return (short)r;
}

typedef __attribute__((address_space(3))) unsigned lds_u;
typedef const __attribute__((address_space(1))) unsigned glb_u;
static __device__ __forceinline__ void gld_lds16(const void* g, void* l) {
    __builtin_amdgcn_global_load_lds((glb_u*)g, (lds_u*)l, 16, 0, 0);
}

// ---------------------------------------------------------------------------
// prep: fp32->bf16 convert (x, ctx) + weight transpose/convert, one launch.
// Blocks [0,7168): convert; [7168,8704): wtrans (block-uniform branch).
// ---------------------------------------------------------------------------
__global__ __launch_bounds__(256) void prep_kernel(
    const float* __restrict__ x, const float* __restrict__ c,
    short* __restrict__ xb, short* __restrict__ cb,
    const float* __restrict__ Wq, const float* __restrict__ Wk,
    const float* __restrict__ Wv, const float* __restrict__ Wo,
    short* __restrict__ wqT, short* __restrict__ wkvT, short* __restrict__ woT)
{
    __shared__ float T[32][33];
    const int bid = blockIdx.x;
    const int tid = threadIdx.x;
    if (bid < 7168) {
        // convert: n1 = 8192*512 (4096 blocks), n2 = 4096*768 (3072 blocks)
        int i = bid * 256 + tid;
        const float* src; short* dst; int off;
        if (i < 1048576) { src = x; dst = xb; off = i; }
        else { src = c; dst = cb; off = i - 1048576; }
        float4 v = ((const float4*)src)[off];
        ushort4 w;
        w.x = (unsigned short)f2bf(v.x); w.y = (unsigned short)f2bf(v.y);
        w.z = (unsigned short)f2bf(v.z); w.w = (unsigned short)f2bf(v.w);
        ((ushort4*)dst)[off] = w;
        return;
    }
    // wtrans: fp32 [R,512] -> bf16 [512,R]
    const int w0 = bid - 7168;
    const int z = w0 / 384, rem = w0 % 384;
    const int yt = rem >> 4, xt = rem & 15;
    const float* src; short* dst; int R;
    if (z == 0)      { src = Wq; dst = wqT;  R = 512; }
    else if (z == 1) { src = Wk; dst = wkvT; R = 768; }
    else if (z == 2) { src = Wv; dst = wkvT + (size_t)512 * 768; R = 768; }
    else             { src = Wo; dst = woT;  R = 512; }
    if (yt * 32 >= R) return;
    {
        int r = tid >> 3, c4 = (tid & 7) * 4;
        float4 v = *(const float4*)&src[(size_t)(yt * 32 + r) * 512 + xt * 32 + c4];
        T[r][c4] = v.x; T[r][c4 + 1] = v.y; T[r][c4 + 2] = v.z; T[r][c4 + 3] = v.w;
    }
    __syncthreads();
    {
        int cc = tid >> 3, r4 = (tid & 7) * 4;
        ushort4 w;
        w.x = (unsigned short)f2bf(T[r4][cc]);     w.y = (unsigned short)f2bf(T[r4 + 1][cc]);
        w.z = (unsigned short)f2bf(T[r4 + 2][cc]); w.w = (unsigned short)f2bf(T[r4 + 3][cc]);
        *(ushort4*)&dst[(size_t)(xt * 32 + cc) * R + yt * 32 + r4] = w;
    }
}

// ---------------------------------------------------------------------------
// Pipelined bf16 GEMM core: acc += A[bm:+128,:K] @ BT[bn:+128,:K]^T.
// 3 LDS buffers, prefetch distance 2, counted vmcnt(4) + raw s_barrier.
// ---------------------------------------------------------------------------
static __device__ __forceinline__ void gemm_core(
    const short* __restrict__ A, const short* __restrict__ BT, int K,
    int bm, int bn, short* As, short* Bs, f32x4 acc[4][4])
{
    const int tid  = threadIdx.x;
    const int lane = tid & 63;
    const int wave = tid >> 6;
    const int lm   = lane & 15;
    const int quad = lane >> 4;
    const int wm = (wave >> 1) * 64;
    const int wn = (wave & 1) * 64;
    const int c = tid >> 7, r = tid & 127;   // staging coords

    const short* Ag = &A[(size_t)(bm + r) * K + c * 8];
    const short* Bg = &BT[(size_t)(bn + r) * K + c * 8];

    // prologue: step 0 -> buf0, step 1 -> buf1 (4 DMA ops per thread per step)
    gld_lds16(Ag,      &As[tid * 8]);
    gld_lds16(Ag + 16, &As[(tid + 256) * 8]);
    gld_lds16(Bg,      &Bs[tid * 8]);
    gld_lds16(Bg + 16, &Bs[(tid + 256) * 8]);
    Ag += 32; Bg += 32;
    gld_lds16(Ag,      &As[4096 + tid * 8]);
    gld_lds16(Ag + 16, &As[4096 + (tid + 256) * 8]);
    gld_lds16(Bg,      &Bs[4096 + tid * 8]);
    gld_lds16(Bg + 16, &Bs[4096 + (tid + 256) * 8]);
    Ag += 32; Bg += 32;

    const int NT = K >> 5;
    int ocur = 0;            // LDS short-offset of step t
    int onxt = 2 * 4096;     // LDS short-offset for step t+2
    for (int t = 0; t < NT; ++t) {
        if (t < NT - 1) asm volatile("s_waitcnt vmcnt(4)" ::: "memory");
        else            asm volatile("s_waitcnt vmcnt(0)" ::: "memory");
        __builtin_amdgcn_s_barrier();
        __builtin_amdgcn_sched_barrier(0);
        if (t < NT - 2) {   // stage step t+2 (its prev readers done at t-1)
            gld_lds16(Ag,      &As[onxt + tid * 8]);
            gld_lds16(Ag + 16, &As[onxt + (tid + 256) * 8]);
            gld_lds16(Bg,      &Bs[onxt + tid * 8]);
            gld_lds16(Bg + 16, &Bs[onxt + (tid + 256) * 8]);
            Ag += 32; Bg += 32;
        }
        const short* Ac = As + ocur;
        const short* Bc = Bs + ocur;
        bf16x8 af[4], bfr[4];
        #pragma unroll
        for (int i = 0; i < 4; ++i)
            af[i] = *(const bf16x8*)&Ac[(quad * 128 + wm + i * 16 + lm) * 8];
        #pragma unroll
        for (int j = 0; j < 4; ++j)
            bfr[j] = *(const bf16x8*)&Bc[(quad * 128 + wn + j * 16 + lm) * 8];
        __builtin_amdgcn_s_setprio(1);
        #pragma unroll
        for (int i = 0; i < 4; ++i)
            #pragma unroll
            for (int j = 0; j < 4; ++j)
                acc[i][j] = __builtin_amdgcn_mfma_f32_16x16x32_bf16(
                    af[i], bfr[j], acc[i][j], 0, 0, 0);
        __builtin_amdgcn_s_setprio(0);
        ocur += 4096; if (ocur == 12288) ocur = 0;
        onxt += 4096; if (onxt == 12288) onxt = 0;
    }
}

// Fused Q + KV projection. Q pre-scaled by C1 = 0.125*log2(e) so attn softmax
// is exp2(S). V tiles write TRANSPOSED + per-64-PERMUTED straight to vT
// (vtrans kernel eliminated): vT[(b*512+dim)*1024 + perm64(n)]; perm preserves
// n&3 so 4 consecutive-n acc values pack into one ushort4. XCD-remapped.
__global__ __launch_bounds__(256) void qkv_kernel(
    const short* __restrict__ xb, const short* __restrict__ cb,
    const short* __restrict__ wqT, const short* __restrict__ wkvT,
    short* __restrict__ qb, short* __restrict__ kvb, short* __restrict__ vT)
{
    __shared__ short As[3 * 4096];
    __shared__ short Bs[3 * 4096];
    const int L = (blockIdx.x & 7) * 64 + (blockIdx.x >> 3);   // bijective, 512
    const short *A, *BT; int K, bm, bn;
    if (L < 256) { A = xb; BT = wqT;  K = 512; bm = (L >> 2) * 128; bn = (L & 3) * 128; }
    else { int b2 = L - 256; A = cb; BT = wkvT; K = 768;
           bm = (b2 >> 3) * 128; bn = (b2 & 7) * 128; }

    f32x4 acc[4][4] = {};
    gemm_core(A, BT, K, bm, bn, As, Bs, acc);

    const int lane = threadIdx.x & 63, wave = threadIdx.x >> 6;
    const int lm = lane & 15, quad = lane >> 4;
    const int wm = (wave >> 1) * 64, wn = (wave & 1) * 64;
    if (L < 256) {
        // Q: scaled so attn softmax is exp2(S) directly
        #pragma unroll
        for (int j = 0; j < 4; ++j) {
            int col = bn + wn + j * 16 + lm;
            #pragma unroll
            for (int i = 0; i < 4; ++i) {
                int row0 = bm + wm + i * 16 + quad * 4;
                #pragma unroll
                for (int r = 0; r < 4; ++r)
                    qb[(size_t)(row0 + r) * 512 + col] = f2bf(acc[i][j][r] * 0.18033688f);
            }
        }
    } else if (bn < 512) {
        // K half: plain write to kvb (ld 1024, cols 0..511; V half unused)
        #pragma unroll
        for (int j = 0; j < 4; ++j) {
            int col = bn + wn + j * 16 + lm;
            #pragma unroll
            for (int i = 0; i < 4; ++i) {
                int row0 = bm + wm + i * 16 + quad * 4;
                #pragma unroll
                for (int r = 0; r < 4; ++r)
                    kvb[(size_t)(row0 + r) * 1024 + col] = f2bf(acc[i][j][r]);
            }
        }
    } else {
        // V half: transposed + permuted direct write to vT
        const int bq = bm >> 10;                 // batch (rows are b*1024+n)
        const int nbase = (bm & 1023) + wm;      // no 1024-crossing: bm%128==0
        #pragma unroll
        for (int j = 0; j < 4; ++j) {
            int dimp = bn + wn + j * 16 + lm - 512;
            short* drow = &vT[((size_t)(bq * 512 + dimp)) * 1024];
            #pragma unroll
            for (int i = 0; i < 4; ++i) {
                int n0 = nbase + i * 16 + quad * 4;     // n0 & 3 == 0
                int nl = n0 & 63;
                int g  = ((nl >> 5) << 2) | ((nl >> 2) & 3);
                int p  = (n0 & ~63) | (g << 3) | (((nl >> 4) & 1) << 2);
                ushort4 w;
                w.x = (unsigned short)f2bf(acc[i][j][0]);
                w.y = (unsigned short)f2bf(acc[i][j][1]);
                w.z = (unsigned short)f2bf(acc[i][j][2]);
                w.w = (unsigned short)f2bf(acc[i][j][3]);
                *(ushort4*)&drow[p] = w;
            }
        }
    }
}

// Output projection: out = ob@woT + bo (fp32 out). Grid 256, XCD-remapped.
__global__ __launch_bounds__(256) void ogemm_kernel(
    const short* __restrict__ ob, const short* __restrict__ woT,
    const float* __restrict__ bias, float* __restrict__ out)
{
    __shared__ short As[3 * 4096];
    __shared__ short Bs[3 * 4096];
    const int L = (blockIdx.x & 7) * 32 + (blockIdx.x >> 3);   // bijective, 256
    const int bm = (L >> 2) * 128, bn = (L & 3) * 128;

    f32x4 acc[4][4] = {};
    gemm_core(ob, woT, 512, bm, bn, As, Bs, acc);

    const int lane = threadIdx.x & 63, wave = threadIdx.x >> 6;
    const int lm = lane & 15, quad = lane >> 4;
    const int wm = (wave >> 1) * 64, wn = (wave & 1) * 64;
    #pragma unroll
    for (int j = 0; j < 4; ++j) {
        int col = bn + wn + j * 16 + lm;
        float bv = bias[col];
        #pragma unroll
        for (int i = 0; i < 4; ++i) {
            int row0 = bm + wm + i * 16 + quad * 4;
            #pragma unroll
            for (int r = 0; r < 4; ++r)
                out[(size_t)(row0 + r) * 512 + col] = acc[i][j][r] + bv;
        }
    }
}

// ---------------------------------------------------------------------------
// Flash attention, in-register P, KVBLK=128, 2-buffer T14 pipeline.
// (R6/R8-verified body, unchanged)
// ---------------------------------------------------------------------------
__global__ __launch_bounds__(256) void attn_kernel(
    const short* __restrict__ q, const short* __restrict__ k,
    const short* __restrict__ vT, short* __restrict__ o)
{
    __shared__ short Ks[2 * 8192];
    __shared__ short Vs[2 * 8192];

    const int tid  = threadIdx.x;
    const int lane = tid & 63;
    const int wave = tid >> 6;
    const int lm   = lane & 15;
    const int quad = lane >> 4;

    // XCD-locality remap: bid = (hb&7) + 8*(qt + 16*(hb>>3)), 512 blocks
    const int bid = blockIdx.x;
    const int xcdq = bid >> 3;                       // 0..63
    const int hb = (bid & 7) + ((xcdq >> 4) << 3);   // 0..31
    const int qt = xcdq & 15;                        // 0..15 (128-row tiles)
    const int h = hb & 7, b = hb >> 3;

    const size_t qrow0 = (size_t)b * 2048 + qt * 128;
    const size_t krow0 = (size_t)b * 1024;
    const int hcol = h * 64;
    const size_t vrow0 = ((size_t)b * 8 + h) * 64;

    // staging coords: K: row rk (0..127), dim-chunk ck (+0/2/4/6);
    //                 V: dim dv (0..63), n-chunk nv (+0/4/8/12)
    const int rk = tid & 127, ck = tid >> 7;
    const int dv = tid & 63,  nv = tid >> 6;
    const short* kg = &k[(krow0 + rk) * 1024 + hcol + ck * 8];
    const short* vg = &vT[(vrow0 + dv) * 1024 + nv * 8];

    // prologue: stage tile 0 (8 DMA ops per thread)
    #pragma unroll
    for (int c = 0; c < 4; ++c)
        gld_lds16(kg + c * 16, &Ks[((ck + 2 * c) * 128 + rk) * 8]);
    #pragma unroll
    for (int c = 0; c < 4; ++c)
        gld_lds16(vg + c * 32, &Vs[((nv + 4 * c) * 64 + dv) * 8]);
    kg += 128 * 1024; vg += 128;

    // Q to registers (after DMA issue; pin keeps them in the preheader)
    const short* qrow0p = &q[(qrow0 + wave * 32 + lm) * 512 + hcol];
    const short* qrow1p = qrow0p + 16 * 512;
    bf16x8 qf00 = *(const bf16x8*)&qrow0p[quad * 8];
    bf16x8 qf01 = *(const bf16x8*)&qrow0p[32 + quad * 8];
    bf16x8 qf10 = *(const bf16x8*)&qrow1p[quad * 8];
    bf16x8 qf11 = *(const bf16x8*)&qrow1p[32 + quad * 8];
    asm volatile("" :: "v"(qf00), "v"(qf01), "v"(qf10), "v"(qf11));

    f32x4 oacc[2][4] = {};
    float lsum[2] = {0.0f, 0.0f};
    const int frk = (quad * 128 + lm) * 8;   // K fragment base (shorts)
    const int frv = (quad * 64 + lm) * 8;    // V fragment base (shorts)

    for (int t = 0; t < 8; ++t) {
        // tile t's 8 DMAs issued one full tile-compute ago -> already landed
        asm volatile("s_waitcnt vmcnt(0)" ::: "memory");
        __builtin_amdgcn_s_barrier();
        __builtin_amdgcn_sched_barrier(0);
        const short* Kc = &Ks[(t & 1) * 8192];
        const short* Vc = &Vs[(t & 1) * 8192];
        if (t < 7) {   // stage tile t+1 into the other buffer (readers done)
            short* Kn = &Ks[((t & 1) ^ 1) * 8192];
            short* Vn = &Vs[((t & 1) ^ 1) * 8192];
            #pragma unroll
            for (int c = 0; c < 4; ++c)
                gld_lds16(kg + c * 16, &Kn[((ck + 2 * c) * 128 + rk) * 8]);
            #pragma unroll
            for (int c = 0; c < 4; ++c)
                gld_lds16(vg + c * 32, &Vn[((nv + 4 * c) * 64 + dv) * 8]);
            kg += 128 * 1024; vg += 128;
        }

        // S^T = K @ Q^T : lane holds q-row lm (per group), k = j*16+quad*4+r
        f32x4 s0[8], s1[8];
        #pragma unroll
        for (int j = 0; j < 8; ++j) { s0[j] = (f32x4){}; s1[j] = (f32x4){}; }
        __builtin_amdgcn_s_setprio(1);
        #pragma unroll
        for (int j = 0; j < 8; ++j) {
            bf16x8 kf0 = *(const bf16x8*)&Kc[frk + j * 128];
            bf16x8 kf1 = *(const bf16x8*)&Kc[frk + 4096 + j * 128];
            s0[j] = __builtin_amdgcn_mfma_f32_16x16x32_bf16(kf0, qf00, s0[j], 0, 0, 0);
            s1[j] = __builtin_amdgcn_mfma_f32_16x16x32_bf16(kf0, qf10, s1[j], 0, 0, 0);
            s0[j] = __builtin_amdgcn_mfma_f32_16x16x32_bf16(kf1, qf01, s0[j], 0, 0, 0);
            s1[j] = __builtin_amdgcn_mfma_f32_16x16x32_bf16(kf1, qf11, s1[j], 0, 0, 0);
        }
        __builtin_amdgcn_s_setprio(0);

        // P = exp2(S); pack pairs to bf16 in-register (PV A-fragments)
        union { unsigned u[4]; bf16x8 v; } pf0[4], pf1[4];
        #pragma unroll
        for (int j = 0; j < 8; ++j) {
            #pragma unroll
            for (int rp = 0; rp < 2; ++rp) {
                float a0 = __builtin_amdgcn_exp2f(s0[j][2 * rp]);
                float a1 = __builtin_amdgcn_exp2f(s0[j][2 * rp + 1]);
                float b0 = __builtin_amdgcn_exp2f(s1[j][2 * rp]);
                float b1 = __builtin_amdgcn_exp2f(s1[j][2 * rp + 1]);
                lsum[0] += a0 + a1;
                lsum[1] += b0 + b1;
                unsigned pa, pb;
                asm("v_cvt_pk_bf16_f32 %0, %1, %2" : "=v"(pa) : "v"(a0), "v"(a1));
                asm("v_cvt_pk_bf16_f32 %0, %1, %2" : "=v"(pb) : "v"(b0), "v"(b1));
                pf0[j >> 1].u[(j & 1) * 2 + rp] = pa;
                pf1[j >> 1].u[(j & 1) * 2 + rp] = pb;
            }
        }

        // O += P @ V : vf chunk (s*4+quad) matches pf_s = pack(s[2s],s[2s+1])
        __builtin_amdgcn_s_setprio(1);
        #pragma unroll
        for (int jd = 0; jd < 4; ++jd) {
            #pragma unroll
            for (int s = 0; s < 4; ++s) {
                bf16x8 vf = *(const bf16x8*)&Vc[frv + s * 2048 + jd * 128];
                oacc[0][jd] = __builtin_amdgcn_mfma_f32_16x16x32_bf16(pf0[s].v, vf, oacc[0][jd], 0, 0, 0);
                oacc[1][jd] = __builtin_amdgcn_mfma_f32_16x16x32_bf16(pf1[s].v, vf, oacc[1][jd], 0, 0, 0);
            }
        }
        __builtin_amdgcn_s_setprio(0);
    }

    // combine the 4 quads' partial row-sums, redistribute to output-row owners
    #pragma unroll
    for (int g = 0; g < 2; ++g) {
        float s = lsum[g];
        s += __shfl_xor(s, 16);
        s += __shfl_xor(s, 32);
        const float inv = 1.0f / s;
        float invr[4];
        #pragma unroll
        for (int r = 0; r < 4; ++r)
            invr[r] = __shfl(inv, quad * 20 + r);   // lane with lm == quad*4+r
        #pragma unroll
        for (int j = 0; j < 4; ++j) {
            int col = hcol + j * 16 + lm;
            #pragma unroll
            for (int r = 0; r < 4; ++r) {
                size_t row = qrow0 + wave * 32 + g * 16 + quad * 4 + r;
                o[row * 512 + col] = f2bf(oacc[g][j][r] * invr[r]);
            }
        }
    }
}

// ---------------------------------------------------------------------------
extern "C" void kernel_launch(void* const* d_in, const int* in_sizes, int n_in,
                              void* d_out, int out_size, void* d_ws, size_t ws_size,
                              hipStream_t stream)
{
    const float* x   = (const float*)d_in[0];
    const float* ctx = (const float*)d_in[1];
    const float* Wq  = (const float*)d_in[2];
    const float* Wk  = (const float*)d_in[3];
    const float* Wv  = (const float*)d_in[4];
    const float* Wo  = (const float*)d_in[5];
    const float* bo  = (const float*)d_in[6];

    char* ws = (char*)d_ws;
    short* xb   = (short*)(ws);                                    // 8 MB
    short* cb   = (short*)(ws + (8u << 20));                       // 6 MB
    short* wqT  = (short*)(ws + (14u << 20));                      // 0.5 MB
    short* wkvT = (short*)(ws + (14u << 20) + (512u << 10));       // 1.5 MB
    short* woT  = (short*)(ws + (16u << 20));                      // 0.5 MB
    short* qb   = (short*)(ws + (16u << 20) + (512u << 10));       // 8 MB
    short* kvb  = (short*)(ws + (24u << 20) + (512u << 10));       // 8 MB
    short* vT   = (short*)(ws + (33u << 20));                      // 4 MB (NOT aliasing cb: written during qkv)
    short* ob   = xb;   // xb dead after QKV GEMM

    prep_kernel<<<8704, 256, 0, stream>>>(x, ctx, xb, cb, Wq, Wk, Wv, Wo, wqT, wkvT, woT);
    qkv_kernel<<<512, 256, 0, stream>>>(xb, cb, wqT, wkvT, qb, kvb, vT);
    attn_kernel<<<512, 256, 0, stream>>>(qb, kvb, vT, ob);
    ogemm_kernel<<<256, 256, 0, stream>>>(ob, woT, bo, (float*)d_out);
}